// Round 1
// baseline (3691.647 us; speedup 1.0000x reference)
//
#include <hip/hip_runtime.h>
#include <hip/hip_bf16.h>

// LlamaMLPInfer: SwiGLU MLP with group(128)-dequantized int4 weights.
// x:[2,2048,4096] f32; gate_q/up_q:[14336,4096] i32; down_q:[4096,14336] i32
// scales f32 [out, in/128]. out:[2,2048,4096] f32.
// Strategy: bf16 MFMA GEMMs (threshold is bf16-scale), on-the-fly dequant of
// weights during LDS staging, fused silu(gate)*up, intermediate in bf16 in ws.

#define HDIM 4096
#define IDIM 14336
#define MTOK 4096
#define GRP 128

typedef __attribute__((ext_vector_type(8))) short bf16x8;
typedef __attribute__((ext_vector_type(4))) float f32x4;
typedef __attribute__((ext_vector_type(8))) unsigned short u16x8;
typedef __attribute__((ext_vector_type(4))) unsigned short u16x4;

__device__ __forceinline__ unsigned short f2bf(float f) {
  union { float f; unsigned int u; } v; v.f = f;
  return (unsigned short)((v.u + 0x7fffu + ((v.u >> 16) & 1u)) >> 16);  // RNE
}

// ---------------- x fp32 -> bf16 ----------------
__global__ __launch_bounds__(256) void cvt_x_kernel(const float* __restrict__ x,
                                                    unsigned short* __restrict__ xb) {
  const int n = MTOK * HDIM;
  const int stride = gridDim.x * 256 * 4;
  for (int i = (blockIdx.x * 256 + threadIdx.x) * 4; i < n; i += stride) {
    float4 v = *reinterpret_cast<const float4*>(x + i);
    u16x4 o;
    o[0] = f2bf(v.x); o[1] = f2bf(v.y); o[2] = f2bf(v.z); o[3] = f2bf(v.w);
    *reinterpret_cast<u16x4*>(xb + i) = o;
  }
}

// ---------------- fused gate+up GEMM ----------------
// C[m,n] = silu(sum_k x[m,k]*Wg[n,k]) * (sum_k x[m,k]*Wu[n,k]), bf16 out.
// 128x128 tile, BK=64, 256 threads (4 waves, 2x2), 16x16x32 bf16 MFMA.
__global__ __launch_bounds__(256, 2) void gateup_kernel(
    const unsigned short* __restrict__ xb,   // [MTOK][HDIM] bf16
    const int* __restrict__ gq, const float* __restrict__ gs,
    const int* __restrict__ uq, const float* __restrict__ us,
    unsigned short* __restrict__ inter)      // [MTOK][IDIM] bf16
{
  __shared__ unsigned short As[128 * 64];
  __shared__ unsigned short Bg[128 * 64];
  __shared__ unsigned short Bu[128 * 64];

  const int tid  = threadIdx.x;
  const int lane = tid & 63;
  const int wid  = tid >> 6;
  const int wm   = wid >> 1, wn = wid & 1;
  const int m0 = blockIdx.x * 128;   // M-tile fast dim -> B-panel sharing in L2/LLC
  const int n0 = blockIdx.y * 128;
  const int lr = lane & 15, lc = lane >> 4;

  f32x4 accg[4][4], accu[4][4];
  const f32x4 zero = {0.f, 0.f, 0.f, 0.f};
#pragma unroll
  for (int i = 0; i < 4; ++i)
#pragma unroll
    for (int j = 0; j < 4; ++j) { accg[i][j] = zero; accu[i][j] = zero; }

  for (int kt = 0; kt < HDIM / 64; ++kt) {
    const int k0 = kt << 6;
    __syncthreads();
    // ---- A tile: global_load_lds, 16B per lane, chunk-linear LDS ----
#pragma unroll
    for (int it = 0; it < 4; ++it) {
      const int c = it * 256 + tid;                       // 0..1023 chunks
      const unsigned short* gp =
          xb + (long)(m0 + (c >> 3)) * HDIM + k0 + ((c & 7) << 3);
      unsigned short* lp = As + (size_t)(it * 256 + (wid << 6)) * 8;  // wave-uniform
      __builtin_amdgcn_global_load_lds(
          (const __attribute__((address_space(1))) unsigned int*)gp,
          (__attribute__((address_space(3))) unsigned int*)lp, 16, 0, 0);
    }
    // ---- B tiles: load int32, dequant to bf16, ds_write 16B chunk-linear ----
#pragma unroll
    for (int it = 0; it < 4; ++it) {
      const int c   = it * 256 + tid;
      const int row = c >> 3;           // 0..127
      const int kc  = (c & 7) << 3;     // 0,8,..,56
      const long gb = (long)(n0 + row) * HDIM + k0 + kc;
      const int  si = (n0 + row) * (HDIM / GRP) + (k0 >> 7);
      {
        const float s = gs[si];
        const int4* p = (const int4*)(gq + gb);
        int4 a0 = p[0], a1 = p[1];
        u16x8 w;
        w[0] = f2bf((float)a0.x * s); w[1] = f2bf((float)a0.y * s);
        w[2] = f2bf((float)a0.z * s); w[3] = f2bf((float)a0.w * s);
        w[4] = f2bf((float)a1.x * s); w[5] = f2bf((float)a1.y * s);
        w[6] = f2bf((float)a1.z * s); w[7] = f2bf((float)a1.w * s);
        *(u16x8*)&Bg[row * 64 + kc] = w;
      }
      {
        const float s = us[si];
        const int4* p = (const int4*)(uq + gb);
        int4 a0 = p[0], a1 = p[1];
        u16x8 w;
        w[0] = f2bf((float)a0.x * s); w[1] = f2bf((float)a0.y * s);
        w[2] = f2bf((float)a0.z * s); w[3] = f2bf((float)a0.w * s);
        w[4] = f2bf((float)a1.x * s); w[5] = f2bf((float)a1.y * s);
        w[6] = f2bf((float)a1.z * s); w[7] = f2bf((float)a1.w * s);
        *(u16x8*)&Bu[row * 64 + kc] = w;
      }
    }
    __syncthreads();
    // ---- MFMA ----
#pragma unroll
    for (int ks = 0; ks < 2; ++ks) {
      const int koff = ks * 32 + lc * 8;
      bf16x8 af[4], bgf[4], buf_[4];
#pragma unroll
      for (int mi = 0; mi < 4; ++mi)
        af[mi] = *(const bf16x8*)&As[(wm * 64 + mi * 16 + lr) * 64 + koff];
#pragma unroll
      for (int ni = 0; ni < 4; ++ni) {
        bgf[ni]  = *(const bf16x8*)&Bg[(wn * 64 + ni * 16 + lr) * 64 + koff];
        buf_[ni] = *(const bf16x8*)&Bu[(wn * 64 + ni * 16 + lr) * 64 + koff];
      }
#pragma unroll
      for (int mi = 0; mi < 4; ++mi)
#pragma unroll
        for (int ni = 0; ni < 4; ++ni) {
          accg[mi][ni] = __builtin_amdgcn_mfma_f32_16x16x32_bf16(
              af[mi], bgf[ni], accg[mi][ni], 0, 0, 0);
          accu[mi][ni] = __builtin_amdgcn_mfma_f32_16x16x32_bf16(
              af[mi], buf_[ni], accu[mi][ni], 0, 0, 0);
        }
    }
  }
  // ---- epilogue: silu(g)*u -> bf16 ----
  const int r0 = m0 + wm * 64, c0 = n0 + wn * 64;
#pragma unroll
  for (int mi = 0; mi < 4; ++mi)
#pragma unroll
    for (int ni = 0; ni < 4; ++ni)
#pragma unroll
      for (int r = 0; r < 4; ++r) {
        float g = accg[mi][ni][r], u = accu[mi][ni][r];
        float sv = g / (1.f + __expf(-g));
        int row = r0 + mi * 16 + lc * 4 + r;
        int col = c0 + ni * 16 + lr;
        inter[(long)row * IDIM + col] = f2bf(sv * u);
      }
}

// ---------------- down GEMM ----------------
// out[m,h] = sum_i inter[m,i] * Wd[h,i], fp32 out.
__global__ __launch_bounds__(256, 2) void down_kernel(
    const unsigned short* __restrict__ inter,  // [MTOK][IDIM] bf16
    const int* __restrict__ dq, const float* __restrict__ dsc,
    float* __restrict__ out)                   // [MTOK][HDIM] f32
{
  __shared__ unsigned short As[128 * 64];
  __shared__ unsigned short Bs[128 * 64];

  const int tid  = threadIdx.x;
  const int lane = tid & 63;
  const int wid  = tid >> 6;
  const int wm   = wid >> 1, wn = wid & 1;
  const int m0 = blockIdx.x * 128;
  const int n0 = blockIdx.y * 128;
  const int lr = lane & 15, lc = lane >> 4;

  f32x4 acc[4][4];
  const f32x4 zero = {0.f, 0.f, 0.f, 0.f};
#pragma unroll
  for (int i = 0; i < 4; ++i)
#pragma unroll
    for (int j = 0; j < 4; ++j) acc[i][j] = zero;

  for (int kt = 0; kt < IDIM / 64; ++kt) {
    const int k0 = kt << 6;
    __syncthreads();
#pragma unroll
    for (int it = 0; it < 4; ++it) {
      const int c = it * 256 + tid;
      const unsigned short* gp =
          inter + (long)(m0 + (c >> 3)) * IDIM + k0 + ((c & 7) << 3);
      unsigned short* lp = As + (size_t)(it * 256 + (wid << 6)) * 8;
      __builtin_amdgcn_global_load_lds(
          (const __attribute__((address_space(1))) unsigned int*)gp,
          (__attribute__((address_space(3))) unsigned int*)lp, 16, 0, 0);
    }
#pragma unroll
    for (int it = 0; it < 4; ++it) {
      const int c   = it * 256 + tid;
      const int row = c >> 3;
      const int kc  = (c & 7) << 3;
      const float s = dsc[(n0 + row) * (IDIM / GRP) + (k0 >> 7)];
      const int4* p = (const int4*)(dq + (long)(n0 + row) * IDIM + k0 + kc);
      int4 a0 = p[0], a1 = p[1];
      u16x8 w;
      w[0] = f2bf((float)a0.x * s); w[1] = f2bf((float)a0.y * s);
      w[2] = f2bf((float)a0.z * s); w[3] = f2bf((float)a0.w * s);
      w[4] = f2bf((float)a1.x * s); w[5] = f2bf((float)a1.y * s);
      w[6] = f2bf((float)a1.z * s); w[7] = f2bf((float)a1.w * s);
      *(u16x8*)&Bs[row * 64 + kc] = w;
    }
    __syncthreads();
#pragma unroll
    for (int ks = 0; ks < 2; ++ks) {
      const int koff = ks * 32 + lc * 8;
      bf16x8 af[4], bf[4];
#pragma unroll
      for (int mi = 0; mi < 4; ++mi)
        af[mi] = *(const bf16x8*)&As[(wm * 64 + mi * 16 + lr) * 64 + koff];
#pragma unroll
      for (int ni = 0; ni < 4; ++ni)
        bf[ni] = *(const bf16x8*)&Bs[(wn * 64 + ni * 16 + lr) * 64 + koff];
#pragma unroll
      for (int mi = 0; mi < 4; ++mi)
#pragma unroll
        for (int ni = 0; ni < 4; ++ni)
          acc[mi][ni] = __builtin_amdgcn_mfma_f32_16x16x32_bf16(
              af[mi], bf[ni], acc[mi][ni], 0, 0, 0);
    }
  }
  const int r0 = m0 + wm * 64, c0 = n0 + wn * 64;
#pragma unroll
  for (int mi = 0; mi < 4; ++mi)
#pragma unroll
    for (int ni = 0; ni < 4; ++ni)
#pragma unroll
      for (int r = 0; r < 4; ++r) {
        int row = r0 + mi * 16 + lc * 4 + r;
        int col = c0 + ni * 16 + lr;
        out[(long)row * HDIM + col] = acc[mi][ni][r];
      }
}

extern "C" void kernel_launch(void* const* d_in, const int* in_sizes, int n_in,
                              void* d_out, int out_size, void* d_ws, size_t ws_size,
                              hipStream_t stream) {
  const float* x   = (const float*)d_in[0];
  const int*   gq  = (const int*)d_in[1];
  const float* gsc = (const float*)d_in[2];
  const int*   uq  = (const int*)d_in[3];
  const float* usc = (const float*)d_in[4];
  const int*   dq  = (const int*)d_in[5];
  const float* dsc = (const float*)d_in[6];
  float* out = (float*)d_out;

  // ws layout: xb [MTOK*HDIM] bf16 (32 MiB) | inter [MTOK*IDIM] bf16 (112 MiB)
  unsigned short* xb    = (unsigned short*)d_ws;
  unsigned short* inter = xb + (size_t)MTOK * HDIM;

  hipLaunchKernelGGL(cvt_x_kernel, dim3(2048), dim3(256), 0, stream, x, xb);
  hipLaunchKernelGGL(gateup_kernel, dim3(32, 112), dim3(256), 0, stream,
                     xb, gq, gsc, uq, usc, inter);
  hipLaunchKernelGGL(down_kernel, dim3(32, 32), dim3(256), 0, stream,
                     inter, dq, dsc, out);
}

// Round 2
// 3354.762 us; speedup vs baseline: 1.1004x; 1.1004x over previous
//
#include <hip/hip_runtime.h>
#include <hip/hip_bf16.h>

// LlamaMLPInfer: SwiGLU MLP with group(128)-dequantized int4 weights.
// x:[2,2048,4096] f32; gate_q/up_q:[14336,4096] i32; down_q:[4096,14336] i32
// scales f32 [out, in/128]. out:[2,2048,4096] f32.
// R1: T2 XOR-swizzle (ch ^= row&7 on 16B chunks) on all LDS tiles.
//   - B tiles: swizzled ds_write + swizzled fragment read.
//   - A tiles (global_load_lds, linear dest): pre-swizzled GLOBAL source col
//     (m173 pattern) + swizzled fragment read.

#define HDIM 4096
#define IDIM 14336
#define MTOK 4096
#define GRP 128

typedef __attribute__((ext_vector_type(8))) short bf16x8;
typedef __attribute__((ext_vector_type(4))) float f32x4;
typedef __attribute__((ext_vector_type(8))) unsigned short u16x8;
typedef __attribute__((ext_vector_type(4))) unsigned short u16x4;

__device__ __forceinline__ unsigned short f2bf(float f) {
  union { float f; unsigned int u; } v; v.f = f;
  return (unsigned short)((v.u + 0x7fffu + ((v.u >> 16) & 1u)) >> 16);  // RNE
}

// ---------------- x fp32 -> bf16 ----------------
__global__ __launch_bounds__(256) void cvt_x_kernel(const float* __restrict__ x,
                                                    unsigned short* __restrict__ xb) {
  const int n = MTOK * HDIM;
  const int stride = gridDim.x * 256 * 4;
  for (int i = (blockIdx.x * 256 + threadIdx.x) * 4; i < n; i += stride) {
    float4 v = *reinterpret_cast<const float4*>(x + i);
    u16x4 o;
    o[0] = f2bf(v.x); o[1] = f2bf(v.y); o[2] = f2bf(v.z); o[3] = f2bf(v.w);
    *reinterpret_cast<u16x4*>(xb + i) = o;
  }
}

// ---------------- fused gate+up GEMM ----------------
// C[m,n] = silu(sum_k x[m,k]*Wg[n,k]) * (sum_k x[m,k]*Wu[n,k]), bf16 out.
// 128x128 tile, BK=64, 256 threads (4 waves, 2x2), 16x16x32 bf16 MFMA.
__global__ __launch_bounds__(256, 2) void gateup_kernel(
    const unsigned short* __restrict__ xb,   // [MTOK][HDIM] bf16
    const int* __restrict__ gq, const float* __restrict__ gs,
    const int* __restrict__ uq, const float* __restrict__ us,
    unsigned short* __restrict__ inter)      // [MTOK][IDIM] bf16
{
  __shared__ unsigned short As[128 * 64];
  __shared__ unsigned short Bg[128 * 64];
  __shared__ unsigned short Bu[128 * 64];

  const int tid  = threadIdx.x;
  const int lane = tid & 63;
  const int wid  = tid >> 6;
  const int wm   = wid >> 1, wn = wid & 1;
  const int m0 = blockIdx.x * 128;   // M-tile fast dim -> B-panel sharing in L2/LLC
  const int n0 = blockIdx.y * 128;
  const int lr = lane & 15, lc = lane >> 4;

  f32x4 accg[4][4], accu[4][4];
  const f32x4 zero = {0.f, 0.f, 0.f, 0.f};
#pragma unroll
  for (int i = 0; i < 4; ++i)
#pragma unroll
    for (int j = 0; j < 4; ++j) { accg[i][j] = zero; accu[i][j] = zero; }

  for (int kt = 0; kt < HDIM / 64; ++kt) {
    const int k0 = kt << 6;
    __syncthreads();
    // ---- A tile: global_load_lds, 16B/lane, linear LDS dest, swizzled src ----
#pragma unroll
    for (int it = 0; it < 4; ++it) {
      const int c   = it * 256 + tid;                 // 0..1023 chunks
      const int row = c >> 3;
      const int scol = ((c & 7) ^ (row & 7)) << 3;    // pre-swizzled source col
      const unsigned short* gp = xb + (long)(m0 + row) * HDIM + k0 + scol;
      unsigned short* lp = As + (size_t)(it * 256 + (wid << 6)) * 8;  // wave-uniform
      __builtin_amdgcn_global_load_lds(
          (const __attribute__((address_space(1))) unsigned int*)gp,
          (__attribute__((address_space(3))) unsigned int*)lp, 16, 0, 0);
    }
    // ---- B tiles: load int32, dequant to bf16, swizzled ds_write ----
#pragma unroll
    for (int it = 0; it < 4; ++it) {
      const int c   = it * 256 + tid;
      const int row = c >> 3;           // 0..127
      const int ch  = c & 7;
      const int kc  = ch << 3;          // global col within K-tile
      const int sidx = row * 64 + ((ch ^ (row & 7)) << 3);  // swizzled LDS idx
      const long gb = (long)(n0 + row) * HDIM + k0 + kc;
      const int  si = (n0 + row) * (HDIM / GRP) + (k0 >> 7);
      {
        const float s = gs[si];
        const int4* p = (const int4*)(gq + gb);
        int4 a0 = p[0], a1 = p[1];
        u16x8 w;
        w[0] = f2bf((float)a0.x * s); w[1] = f2bf((float)a0.y * s);
        w[2] = f2bf((float)a0.z * s); w[3] = f2bf((float)a0.w * s);
        w[4] = f2bf((float)a1.x * s); w[5] = f2bf((float)a1.y * s);
        w[6] = f2bf((float)a1.z * s); w[7] = f2bf((float)a1.w * s);
        *(u16x8*)&Bg[sidx] = w;
      }
      {
        const float s = us[si];
        const int4* p = (const int4*)(uq + gb);
        int4 a0 = p[0], a1 = p[1];
        u16x8 w;
        w[0] = f2bf((float)a0.x * s); w[1] = f2bf((float)a0.y * s);
        w[2] = f2bf((float)a0.z * s); w[3] = f2bf((float)a0.w * s);
        w[4] = f2bf((float)a1.x * s); w[5] = f2bf((float)a1.y * s);
        w[6] = f2bf((float)a1.z * s); w[7] = f2bf((float)a1.w * s);
        *(u16x8*)&Bu[sidx] = w;
      }
    }
    __syncthreads();
    // ---- MFMA (swizzled fragment reads; row&7 == lr&7) ----
#pragma unroll
    for (int ks = 0; ks < 2; ++ks) {
      const int ch   = (ks << 2);  // + lc below
      const int soff = ((ch + lc) ^ (lr & 7)) << 3;
      bf16x8 af[4], bgf[4], buf_[4];
#pragma unroll
      for (int mi = 0; mi < 4; ++mi)
        af[mi] = *(const bf16x8*)&As[(wm * 64 + mi * 16 + lr) * 64 + soff];
#pragma unroll
      for (int ni = 0; ni < 4; ++ni) {
        bgf[ni]  = *(const bf16x8*)&Bg[(wn * 64 + ni * 16 + lr) * 64 + soff];
        buf_[ni] = *(const bf16x8*)&Bu[(wn * 64 + ni * 16 + lr) * 64 + soff];
      }
#pragma unroll
      for (int mi = 0; mi < 4; ++mi)
#pragma unroll
        for (int ni = 0; ni < 4; ++ni) {
          accg[mi][ni] = __builtin_amdgcn_mfma_f32_16x16x32_bf16(
              af[mi], bgf[ni], accg[mi][ni], 0, 0, 0);
          accu[mi][ni] = __builtin_amdgcn_mfma_f32_16x16x32_bf16(
              af[mi], buf_[ni], accu[mi][ni], 0, 0, 0);
        }
    }
  }
  // ---- epilogue: silu(g)*u -> bf16 ----
  const int r0 = m0 + wm * 64, c0 = n0 + wn * 64;
#pragma unroll
  for (int mi = 0; mi < 4; ++mi)
#pragma unroll
    for (int ni = 0; ni < 4; ++ni)
#pragma unroll
      for (int r = 0; r < 4; ++r) {
        float g = accg[mi][ni][r], u = accu[mi][ni][r];
        float sv = g / (1.f + __expf(-g));
        int row = r0 + mi * 16 + lc * 4 + r;
        int col = c0 + ni * 16 + lr;
        inter[(long)row * IDIM + col] = f2bf(sv * u);
      }
}

// ---------------- down GEMM ----------------
// out[m,h] = sum_i inter[m,i] * Wd[h,i], fp32 out.
__global__ __launch_bounds__(256, 2) void down_kernel(
    const unsigned short* __restrict__ inter,  // [MTOK][IDIM] bf16
    const int* __restrict__ dq, const float* __restrict__ dsc,
    float* __restrict__ out)                   // [MTOK][HDIM] f32
{
  __shared__ unsigned short As[128 * 64];
  __shared__ unsigned short Bs[128 * 64];

  const int tid  = threadIdx.x;
  const int lane = tid & 63;
  const int wid  = tid >> 6;
  const int wm   = wid >> 1, wn = wid & 1;
  const int m0 = blockIdx.x * 128;
  const int n0 = blockIdx.y * 128;
  const int lr = lane & 15, lc = lane >> 4;

  f32x4 acc[4][4];
  const f32x4 zero = {0.f, 0.f, 0.f, 0.f};
#pragma unroll
  for (int i = 0; i < 4; ++i)
#pragma unroll
    for (int j = 0; j < 4; ++j) acc[i][j] = zero;

  for (int kt = 0; kt < IDIM / 64; ++kt) {
    const int k0 = kt << 6;
    __syncthreads();
#pragma unroll
    for (int it = 0; it < 4; ++it) {
      const int c   = it * 256 + tid;
      const int row = c >> 3;
      const int scol = ((c & 7) ^ (row & 7)) << 3;
      const unsigned short* gp = inter + (long)(m0 + row) * IDIM + k0 + scol;
      unsigned short* lp = As + (size_t)(it * 256 + (wid << 6)) * 8;
      __builtin_amdgcn_global_load_lds(
          (const __attribute__((address_space(1))) unsigned int*)gp,
          (__attribute__((address_space(3))) unsigned int*)lp, 16, 0, 0);
    }
#pragma unroll
    for (int it = 0; it < 4; ++it) {
      const int c   = it * 256 + tid;
      const int row = c >> 3;
      const int ch  = c & 7;
      const int kc  = ch << 3;
      const int sidx = row * 64 + ((ch ^ (row & 7)) << 3);
      const float s = dsc[(n0 + row) * (IDIM / GRP) + (k0 >> 7)];
      const int4* p = (const int4*)(dq + (long)(n0 + row) * IDIM + k0 + kc);
      int4 a0 = p[0], a1 = p[1];
      u16x8 w;
      w[0] = f2bf((float)a0.x * s); w[1] = f2bf((float)a0.y * s);
      w[2] = f2bf((float)a0.z * s); w[3] = f2bf((float)a0.w * s);
      w[4] = f2bf((float)a1.x * s); w[5] = f2bf((float)a1.y * s);
      w[6] = f2bf((float)a1.z * s); w[7] = f2bf((float)a1.w * s);
      *(u16x8*)&Bs[sidx] = w;
    }
    __syncthreads();
#pragma unroll
    for (int ks = 0; ks < 2; ++ks) {
      const int soff = (((ks << 2) + lc) ^ (lr & 7)) << 3;
      bf16x8 af[4], bf[4];
#pragma unroll
      for (int mi = 0; mi < 4; ++mi)
        af[mi] = *(const bf16x8*)&As[(wm * 64 + mi * 16 + lr) * 64 + soff];
#pragma unroll
      for (int ni = 0; ni < 4; ++ni)
        bf[ni] = *(const bf16x8*)&Bs[(wn * 64 + ni * 16 + lr) * 64 + soff];
#pragma unroll
      for (int mi = 0; mi < 4; ++mi)
#pragma unroll
        for (int ni = 0; ni < 4; ++ni)
          acc[mi][ni] = __builtin_amdgcn_mfma_f32_16x16x32_bf16(
              af[mi], bf[ni], acc[mi][ni], 0, 0, 0);
    }
  }
  const int r0 = m0 + wm * 64, c0 = n0 + wn * 64;
#pragma unroll
  for (int mi = 0; mi < 4; ++mi)
#pragma unroll
    for (int ni = 0; ni < 4; ++ni)
#pragma unroll
      for (int r = 0; r < 4; ++r) {
        int row = r0 + mi * 16 + lc * 4 + r;
        int col = c0 + ni * 16 + lr;
        out[(long)row * HDIM + col] = acc[mi][ni][r];
      }
}

extern "C" void kernel_launch(void* const* d_in, const int* in_sizes, int n_in,
                              void* d_out, int out_size, void* d_ws, size_t ws_size,
                              hipStream_t stream) {
  const float* x   = (const float*)d_in[0];
  const int*   gq  = (const int*)d_in[1];
  const float* gsc = (const float*)d_in[2];
  const int*   uq  = (const int*)d_in[3];
  const float* usc = (const float*)d_in[4];
  const int*   dq  = (const int*)d_in[5];
  const float* dsc = (const float*)d_in[6];
  float* out = (float*)d_out;

  // ws layout: xb [MTOK*HDIM] bf16 (32 MiB) | inter [MTOK*IDIM] bf16 (112 MiB)
  unsigned short* xb    = (unsigned short*)d_ws;
  unsigned short* inter = xb + (size_t)MTOK * HDIM;

  hipLaunchKernelGGL(cvt_x_kernel, dim3(2048), dim3(256), 0, stream, x, xb);
  hipLaunchKernelGGL(gateup_kernel, dim3(32, 112), dim3(256), 0, stream,
                     xb, gq, gsc, uq, usc, inter);
  hipLaunchKernelGGL(down_kernel, dim3(32, 32), dim3(256), 0, stream,
                     inter, dq, dsc, out);
}

// Round 3
// 2481.016 us; speedup vs baseline: 1.4880x; 1.3522x over previous
//
#include <hip/hip_runtime.h>
#include <hip/hip_bf16.h>

// LlamaMLPInfer: SwiGLU MLP with group(128)-dequantized int4 weights.
// R2: 256x128 tile, 512 thr (8 waves, 4Mx2N), BK=64.
//  - A: global_load_lds into DOUBLE-buffered LDS, pre-swizzled source cols.
//  - B: int32 -> regs prefetched one K-step ahead (T14), dequant (truncating
//    v_perm pack) + swizzled ds_write after the read-barrier.
//  - 2 barriers/K-step, loads for t+1 in flight across compute of t.

#define HDIM 4096
#define IDIM 14336
#define MTOK 4096
#define GRP 128

typedef __attribute__((ext_vector_type(8))) short bf16x8;
typedef __attribute__((ext_vector_type(4))) float f32x4;
typedef __attribute__((ext_vector_type(4))) unsigned short u16x4;

__device__ __forceinline__ unsigned short f2bf(float f) {
  union { float f; unsigned int u; } v; v.f = f;
  return (unsigned short)((v.u + 0x7fffu + ((v.u >> 16) & 1u)) >> 16);  // RNE
}
// pack two f32 -> two bf16 (truncate): low16 = bf16(a), high16 = bf16(b)
__device__ __forceinline__ unsigned pk2(float a, float b) {
  union { float f; unsigned u; } ua, ub; ua.f = a; ub.f = b;
  return __builtin_amdgcn_perm(ub.u, ua.u, 0x07060302u);
}

// ---------------- x fp32 -> bf16 ----------------
__global__ __launch_bounds__(256) void cvt_x_kernel(const float* __restrict__ x,
                                                    unsigned short* __restrict__ xb) {
  const int n = MTOK * HDIM;
  const int stride = gridDim.x * 256 * 4;
  for (int i = (blockIdx.x * 256 + threadIdx.x) * 4; i < n; i += stride) {
    float4 v = *reinterpret_cast<const float4*>(x + i);
    u16x4 o;
    o[0] = f2bf(v.x); o[1] = f2bf(v.y); o[2] = f2bf(v.z); o[3] = f2bf(v.w);
    *reinterpret_cast<u16x4*>(xb + i) = o;
  }
}

// ---------------- fused gate+up GEMM ----------------
__global__ __launch_bounds__(512, 2) void gateup_kernel(
    const unsigned short* __restrict__ xb,   // [MTOK][HDIM] bf16
    const int* __restrict__ gq, const float* __restrict__ gs,
    const int* __restrict__ uq, const float* __restrict__ us,
    unsigned short* __restrict__ inter)      // [MTOK][IDIM] bf16
{
  __shared__ unsigned short As[2 * 256 * 64];  // 64 KB double-buffered
  __shared__ unsigned short Bg[128 * 64];      // 16 KB
  __shared__ unsigned short Bu[128 * 64];      // 16 KB

  const int tid  = threadIdx.x;                 // 0..511
  const int lane = tid & 63;
  const int wid  = tid >> 6;                    // 0..7
  const int wm   = wid >> 1, wn = wid & 1;      // 4M x 2N
  const int m0 = blockIdx.x * 256;
  const int n0 = blockIdx.y * 128;
  const int lr = lane & 15, lc = lane >> 4;

  // ---- A staging constants (global_load_lds, linear dest, pre-swizzled src)
  const int ra   = tid >> 3;                          // 0..63 (+ it*64)
  const int scol = ((tid & 7) ^ (ra & 7)) << 3;       // pre-swizzled source col
  const unsigned short* pa = xb + (long)(m0 + ra) * HDIM + scol;
  unsigned short* lbase = (unsigned short*)As + wid * 512;  // wave-uniform

  // ---- B staging constants (reg-staged, swizzled ds_write)
  const int rb  = tid >> 3;                           // 0..63 (+ j*64)
  const int cb  = (tid & 7) << 3;                     // int col in K-tile
  const int swz = ((tid & 7) ^ (rb & 7)) << 3;
  const int sidx0 = rb * 64 + swz;
  const int sidx1 = (64 + rb) * 64 + swz;
  const int*   pg0 = gq + (long)(n0 + rb) * HDIM + cb;
  const int*   pg1 = pg0 + 64 * HDIM;
  const int*   pu0 = uq + (long)(n0 + rb) * HDIM + cb;
  const int*   pu1 = pu0 + 64 * HDIM;
  const float* psg0 = gs + (n0 + rb) * (HDIM / GRP);
  const float* psg1 = psg0 + 64 * (HDIM / GRP);
  const float* psu0 = us + (n0 + rb) * (HDIM / GRP);
  const float* psu1 = psu0 + 64 * (HDIM / GRP);

  // B prefetch registers (named -> no scratch)
  int4 g0a, g0b, g1a, g1b, u0a, u0b, u1a, u1b;
  float s0g, s1g, s0u, s1u;

  auto issueA = [&](int kt, int ab) {
    const unsigned short* g = pa + kt * 64;
    unsigned short* l = lbase + ab * 16384;
#pragma unroll
    for (int it = 0; it < 4; ++it) {
      __builtin_amdgcn_global_load_lds(
          (const __attribute__((address_space(1))) unsigned int*)(g + it * 64 * HDIM),
          (__attribute__((address_space(3))) unsigned int*)(l + it * 4096), 16, 0, 0);
    }
  };
  auto loadB = [&](int kt) {
    const int k = kt * 64;
    const int so = kt >> 1;
    g0a = ((const int4*)(pg0 + k))[0]; g0b = ((const int4*)(pg0 + k))[1];
    g1a = ((const int4*)(pg1 + k))[0]; g1b = ((const int4*)(pg1 + k))[1];
    u0a = ((const int4*)(pu0 + k))[0]; u0b = ((const int4*)(pu0 + k))[1];
    u1a = ((const int4*)(pu1 + k))[0]; u1b = ((const int4*)(pu1 + k))[1];
    s0g = psg0[so]; s1g = psg1[so]; s0u = psu0[so]; s1u = psu1[so];
  };
  auto writeB = [&]() {
    uint4 w;
    w.x = pk2((float)g0a.x * s0g, (float)g0a.y * s0g);
    w.y = pk2((float)g0a.z * s0g, (float)g0a.w * s0g);
    w.z = pk2((float)g0b.x * s0g, (float)g0b.y * s0g);
    w.w = pk2((float)g0b.z * s0g, (float)g0b.w * s0g);
    *(uint4*)&Bg[sidx0] = w;
    w.x = pk2((float)g1a.x * s1g, (float)g1a.y * s1g);
    w.y = pk2((float)g1a.z * s1g, (float)g1a.w * s1g);
    w.z = pk2((float)g1b.x * s1g, (float)g1b.y * s1g);
    w.w = pk2((float)g1b.z * s1g, (float)g1b.w * s1g);
    *(uint4*)&Bg[sidx1] = w;
    w.x = pk2((float)u0a.x * s0u, (float)u0a.y * s0u);
    w.y = pk2((float)u0a.z * s0u, (float)u0a.w * s0u);
    w.z = pk2((float)u0b.x * s0u, (float)u0b.y * s0u);
    w.w = pk2((float)u0b.z * s0u, (float)u0b.w * s0u);
    *(uint4*)&Bu[sidx0] = w;
    w.x = pk2((float)u1a.x * s1u, (float)u1a.y * s1u);
    w.y = pk2((float)u1a.z * s1u, (float)u1a.w * s1u);
    w.z = pk2((float)u1b.x * s1u, (float)u1b.y * s1u);
    w.w = pk2((float)u1b.z * s1u, (float)u1b.w * s1u);
    *(uint4*)&Bu[sidx1] = w;
  };

  f32x4 accg[4][4], accu[4][4];
  const f32x4 zero = {0.f, 0.f, 0.f, 0.f};
#pragma unroll
  for (int i = 0; i < 4; ++i)
#pragma unroll
    for (int j = 0; j < 4; ++j) { accg[i][j] = zero; accu[i][j] = zero; }

  // prologue: stage tile 0
  issueA(0, 0);
  loadB(0);
  writeB();
  __syncthreads();

  const int NK = HDIM / 64;
  for (int kt = 0; kt < NK; ++kt) {
    const int cur = kt & 1;
    const bool pf = (kt + 1 < NK);
    if (pf) { issueA(kt + 1, cur ^ 1); loadB(kt + 1); }
    // ---- compute tile kt ----
    const unsigned short* Ab = (const unsigned short*)As + cur * 16384;
#pragma unroll
    for (int ks = 0; ks < 2; ++ks) {
      const int soff = (((ks << 2) + lc) ^ (lr & 7)) << 3;
      bf16x8 af[4];
#pragma unroll
      for (int mi = 0; mi < 4; ++mi)
        af[mi] = *(const bf16x8*)&Ab[(wm * 64 + mi * 16 + lr) * 64 + soff];
#pragma unroll
      for (int ni = 0; ni < 4; ++ni) {
        bf16x8 bg = *(const bf16x8*)&Bg[(wn * 64 + ni * 16 + lr) * 64 + soff];
        bf16x8 bu = *(const bf16x8*)&Bu[(wn * 64 + ni * 16 + lr) * 64 + soff];
#pragma unroll
        for (int mi = 0; mi < 4; ++mi) {
          accg[mi][ni] = __builtin_amdgcn_mfma_f32_16x16x32_bf16(af[mi], bg, accg[mi][ni], 0, 0, 0);
          accu[mi][ni] = __builtin_amdgcn_mfma_f32_16x16x32_bf16(af[mi], bu, accu[mi][ni], 0, 0, 0);
        }
      }
    }
    __syncthreads();          // all waves done reading LDS tile kt
    if (pf) writeB();         // dequant t+1 (vmcnt wait here), ds_write
    __syncthreads();          // writes visible
  }

  // ---- epilogue: silu(g)*u -> bf16 ----
  const int r0 = m0 + wm * 64, c0 = n0 + wn * 64;
#pragma unroll
  for (int mi = 0; mi < 4; ++mi)
#pragma unroll
    for (int ni = 0; ni < 4; ++ni)
#pragma unroll
      for (int r = 0; r < 4; ++r) {
        float g = accg[mi][ni][r], u = accu[mi][ni][r];
        float sv = g / (1.f + __expf(-g));
        int row = r0 + mi * 16 + lc * 4 + r;
        int col = c0 + ni * 16 + lr;
        inter[(long)row * IDIM + col] = f2bf(sv * u);
      }
}

// ---------------- down GEMM ----------------
__global__ __launch_bounds__(512, 2) void down_kernel(
    const unsigned short* __restrict__ inter,  // [MTOK][IDIM] bf16
    const int* __restrict__ dq, const float* __restrict__ dsc,
    float* __restrict__ out)                   // [MTOK][HDIM] f32
{
  __shared__ unsigned short As[2 * 256 * 64];  // 64 KB dbuf
  __shared__ unsigned short Bs[128 * 64];      // 16 KB

  const int tid  = threadIdx.x;
  const int lane = tid & 63;
  const int wid  = tid >> 6;
  const int wm   = wid >> 1, wn = wid & 1;
  const int m0 = blockIdx.x * 256;
  const int n0 = blockIdx.y * 128;
  const int lr = lane & 15, lc = lane >> 4;

  const int ra   = tid >> 3;
  const int scol = ((tid & 7) ^ (ra & 7)) << 3;
  const unsigned short* pa = inter + (long)(m0 + ra) * IDIM + scol;
  unsigned short* lbase = (unsigned short*)As + wid * 512;

  const int rb  = tid >> 3;
  const int cb  = (tid & 7) << 3;
  const int swz = ((tid & 7) ^ (rb & 7)) << 3;
  const int sidx0 = rb * 64 + swz;
  const int sidx1 = (64 + rb) * 64 + swz;
  const int*   pd0 = dq + (long)(n0 + rb) * IDIM + cb;
  const int*   pd1 = pd0 + 64 * IDIM;
  const float* ps0 = dsc + (n0 + rb) * (IDIM / GRP);
  const float* ps1 = ps0 + 64 * (IDIM / GRP);

  int4 d0a, d0b, d1a, d1b;
  float s0, s1;

  auto issueA = [&](int kt, int ab) {
    const unsigned short* g = pa + kt * 64;
    unsigned short* l = lbase + ab * 16384;
#pragma unroll
    for (int it = 0; it < 4; ++it) {
      __builtin_amdgcn_global_load_lds(
          (const __attribute__((address_space(1))) unsigned int*)(g + it * 64 * IDIM),
          (__attribute__((address_space(3))) unsigned int*)(l + it * 4096), 16, 0, 0);
    }
  };
  auto loadB = [&](int kt) {
    const int k = kt * 64;
    const int so = kt >> 1;
    d0a = ((const int4*)(pd0 + k))[0]; d0b = ((const int4*)(pd0 + k))[1];
    d1a = ((const int4*)(pd1 + k))[0]; d1b = ((const int4*)(pd1 + k))[1];
    s0 = ps0[so]; s1 = ps1[so];
  };
  auto writeB = [&]() {
    uint4 w;
    w.x = pk2((float)d0a.x * s0, (float)d0a.y * s0);
    w.y = pk2((float)d0a.z * s0, (float)d0a.w * s0);
    w.z = pk2((float)d0b.x * s0, (float)d0b.y * s0);
    w.w = pk2((float)d0b.z * s0, (float)d0b.w * s0);
    *(uint4*)&Bs[sidx0] = w;
    w.x = pk2((float)d1a.x * s1, (float)d1a.y * s1);
    w.y = pk2((float)d1a.z * s1, (float)d1a.w * s1);
    w.z = pk2((float)d1b.x * s1, (float)d1b.y * s1);
    w.w = pk2((float)d1b.z * s1, (float)d1b.w * s1);
    *(uint4*)&Bs[sidx1] = w;
  };

  f32x4 acc[4][4];
  const f32x4 zero = {0.f, 0.f, 0.f, 0.f};
#pragma unroll
  for (int i = 0; i < 4; ++i)
#pragma unroll
    for (int j = 0; j < 4; ++j) acc[i][j] = zero;

  issueA(0, 0);
  loadB(0);
  writeB();
  __syncthreads();

  const int NK = IDIM / 64;
  for (int kt = 0; kt < NK; ++kt) {
    const int cur = kt & 1;
    const bool pf = (kt + 1 < NK);
    if (pf) { issueA(kt + 1, cur ^ 1); loadB(kt + 1); }
    const unsigned short* Ab = (const unsigned short*)As + cur * 16384;
#pragma unroll
    for (int ks = 0; ks < 2; ++ks) {
      const int soff = (((ks << 2) + lc) ^ (lr & 7)) << 3;
      bf16x8 af[4];
#pragma unroll
      for (int mi = 0; mi < 4; ++mi)
        af[mi] = *(const bf16x8*)&Ab[(wm * 64 + mi * 16 + lr) * 64 + soff];
#pragma unroll
      for (int ni = 0; ni < 4; ++ni) {
        bf16x8 bs = *(const bf16x8*)&Bs[(wn * 64 + ni * 16 + lr) * 64 + soff];
#pragma unroll
        for (int mi = 0; mi < 4; ++mi)
          acc[mi][ni] = __builtin_amdgcn_mfma_f32_16x16x32_bf16(af[mi], bs, acc[mi][ni], 0, 0, 0);
      }
    }
    __syncthreads();
    if (pf) writeB();
    __syncthreads();
  }

  const int r0 = m0 + wm * 64, c0 = n0 + wn * 64;
#pragma unroll
  for (int mi = 0; mi < 4; ++mi)
#pragma unroll
    for (int ni = 0; ni < 4; ++ni)
#pragma unroll
      for (int r = 0; r < 4; ++r) {
        int row = r0 + mi * 16 + lc * 4 + r;
        int col = c0 + ni * 16 + lr;
        out[(long)row * HDIM + col] = acc[mi][ni][r];
      }
}

extern "C" void kernel_launch(void* const* d_in, const int* in_sizes, int n_in,
                              void* d_out, int out_size, void* d_ws, size_t ws_size,
                              hipStream_t stream) {
  const float* x   = (const float*)d_in[0];
  const int*   gq  = (const int*)d_in[1];
  const float* gsc = (const float*)d_in[2];
  const int*   uq  = (const int*)d_in[3];
  const float* usc = (const float*)d_in[4];
  const int*   dq  = (const int*)d_in[5];
  const float* dsc = (const float*)d_in[6];
  float* out = (float*)d_out;

  // ws layout: xb [MTOK*HDIM] bf16 (32 MiB) | inter [MTOK*IDIM] bf16 (112 MiB)
  unsigned short* xb    = (unsigned short*)d_ws;
  unsigned short* inter = xb + (size_t)MTOK * HDIM;

  hipLaunchKernelGGL(cvt_x_kernel, dim3(2048), dim3(256), 0, stream, x, xb);
  hipLaunchKernelGGL(gateup_kernel, dim3(16, 112), dim3(512), 0, stream,
                     xb, gq, gsc, uq, usc, inter);
  hipLaunchKernelGGL(down_kernel, dim3(16, 32), dim3(512), 0, stream,
                     inter, dq, dsc, out);
}

// Round 4
// 2077.593 us; speedup vs baseline: 1.7769x; 1.1942x over previous
//
#include <hip/hip_runtime.h>
#include <hip/hip_bf16.h>

// LlamaMLPInfer: SwiGLU MLP with group(128)-dequantized int4 weights.
// R4: XCD-chunked block swizzle (T1), single-barrier K-loop for gateup
// (B_lds double-buffered, writeB pre-barrier), counted-vmcnt cross-barrier
// pipeline for down (T3/T4-minimum), setprio around MFMA (T5).

#define HDIM 4096
#define IDIM 14336
#define MTOK 4096
#define GRP 128

typedef __attribute__((ext_vector_type(8))) short bf16x8;
typedef __attribute__((ext_vector_type(4))) float f32x4;
typedef __attribute__((ext_vector_type(4))) unsigned short u16x4;

__device__ __forceinline__ unsigned short f2bf(float f) {
  union { float f; unsigned int u; } v; v.f = f;
  return (unsigned short)((v.u + 0x7fffu + ((v.u >> 16) & 1u)) >> 16);  // RNE
}
// pack two f32 -> two bf16 (truncate): low16 = bf16(a), high16 = bf16(b)
__device__ __forceinline__ unsigned pk2(float a, float b) {
  union { float f; unsigned u; } ua, ub; ua.f = a; ub.f = b;
  return __builtin_amdgcn_perm(ub.u, ua.u, 0x07060302u);
}

// ---------------- x fp32 -> bf16 ----------------
__global__ __launch_bounds__(256) void cvt_x_kernel(const float* __restrict__ x,
                                                    unsigned short* __restrict__ xb) {
  const int n = MTOK * HDIM;
  const int stride = gridDim.x * 256 * 4;
  for (int i = (blockIdx.x * 256 + threadIdx.x) * 4; i < n; i += stride) {
    float4 v = *reinterpret_cast<const float4*>(x + i);
    u16x4 o;
    o[0] = f2bf(v.x); o[1] = f2bf(v.y); o[2] = f2bf(v.z); o[3] = f2bf(v.w);
    *reinterpret_cast<u16x4*>(xb + i) = o;
  }
}

// ================= fused gate+up GEMM =================
// 256x128 tile, BK=64, 512 thr (8 waves, 4Mx2N). Single barrier per K-step.
__global__ __launch_bounds__(512, 2) void gateup_kernel(
    const unsigned short* __restrict__ xb,
    const int* __restrict__ gq, const float* __restrict__ gs,
    const int* __restrict__ uq, const float* __restrict__ us,
    unsigned short* __restrict__ inter)
{
  __shared__ unsigned short As[2 * 256 * 64];  // 64 KB dbuf
  __shared__ unsigned short Bg[2 * 128 * 64];  // 32 KB dbuf
  __shared__ unsigned short Bu[2 * 128 * 64];  // 32 KB dbuf

  const int tid  = threadIdx.x;
  const int lane = tid & 63;
  const int wid  = tid >> 6;
  const int wm   = wid >> 1, wn = wid & 1;
  // XCD-chunked swizzle: 1792 blocks, 8 XCDs, 224 contiguous logicals per XCD.
  const int p  = blockIdx.x;
  const int l  = (p & 7) * 224 + (p >> 3);
  const int m0 = (l & 15) * 256;
  const int n0 = (l >> 4) * 128;
  const int lr = lane & 15, lc = lane >> 4;

  // A staging (global_load_lds, linear dest, pre-swizzled source col)
  const int ra   = tid >> 3;
  const int scol = ((tid & 7) ^ (ra & 7)) << 3;
  const unsigned short* pa = xb + (long)(m0 + ra) * HDIM + scol;
  unsigned short* lbase = (unsigned short*)As + wid * 512;

  // B staging (reg-staged, swizzled ds_write)
  const int rb  = tid >> 3;
  const int cb  = (tid & 7) << 3;
  const int swz = ((tid & 7) ^ (rb & 7)) << 3;
  const int sidx0 = rb * 64 + swz;
  const int sidx1 = (64 + rb) * 64 + swz;
  const int*   pg0 = gq + (long)(n0 + rb) * HDIM + cb;
  const int*   pg1 = pg0 + 64 * HDIM;
  const int*   pu0 = uq + (long)(n0 + rb) * HDIM + cb;
  const int*   pu1 = pu0 + 64 * HDIM;
  const float* psg0 = gs + (n0 + rb) * (HDIM / GRP);
  const float* psg1 = psg0 + 64 * (HDIM / GRP);
  const float* psu0 = us + (n0 + rb) * (HDIM / GRP);
  const float* psu1 = psu0 + 64 * (HDIM / GRP);

  int4 q[8];       // this-iteration raw weights (depth-1)
  float sc[4];

#define GU_ISSUEA(KTA, WRP) do {                                              \
    const unsigned short* g_ = pa + (KTA) * 64;                               \
    unsigned short* l_ = lbase + (WRP) * 16384;                               \
    _Pragma("unroll")                                                         \
    for (int it = 0; it < 4; ++it)                                            \
      __builtin_amdgcn_global_load_lds(                                       \
          (const __attribute__((address_space(1))) unsigned int*)(g_ + it * 64 * HDIM), \
          (__attribute__((address_space(3))) unsigned int*)(l_ + it * 4096), 16, 0, 0); \
  } while (0)

#define GU_LOADB(KT) do { const int kk_ = (KT) << 6;                          \
    q[0] = *(const int4*)(pg0 + kk_); q[1] = *(const int4*)(pg0 + kk_ + 4);   \
    q[2] = *(const int4*)(pg1 + kk_); q[3] = *(const int4*)(pg1 + kk_ + 4);   \
    q[4] = *(const int4*)(pu0 + kk_); q[5] = *(const int4*)(pu0 + kk_ + 4);   \
    q[6] = *(const int4*)(pu1 + kk_); q[7] = *(const int4*)(pu1 + kk_ + 4);   \
    const int so_ = (KT) >> 1;                                                \
    sc[0] = psg0[so_]; sc[1] = psg1[so_]; sc[2] = psu0[so_]; sc[3] = psu1[so_]; \
  } while (0)

#define GU_WRITEB(WRP) do {                                                   \
    unsigned short* Bg_ = (unsigned short*)Bg + (WRP) * 8192;                 \
    unsigned short* Bu_ = (unsigned short*)Bu + (WRP) * 8192;                 \
    uint4 w_;                                                                 \
    w_.x = pk2((float)q[0].x * sc[0], (float)q[0].y * sc[0]);                 \
    w_.y = pk2((float)q[0].z * sc[0], (float)q[0].w * sc[0]);                 \
    w_.z = pk2((float)q[1].x * sc[0], (float)q[1].y * sc[0]);                 \
    w_.w = pk2((float)q[1].z * sc[0], (float)q[1].w * sc[0]);                 \
    *(uint4*)&Bg_[sidx0] = w_;                                                \
    w_.x = pk2((float)q[2].x * sc[1], (float)q[2].y * sc[1]);                 \
    w_.y = pk2((float)q[2].z * sc[1], (float)q[2].w * sc[1]);                 \
    w_.z = pk2((float)q[3].x * sc[1], (float)q[3].y * sc[1]);                 \
    w_.w = pk2((float)q[3].z * sc[1], (float)q[3].w * sc[1]);                 \
    *(uint4*)&Bg_[sidx1] = w_;                                                \
    w_.x = pk2((float)q[4].x * sc[2], (float)q[4].y * sc[2]);                 \
    w_.y = pk2((float)q[4].z * sc[2], (float)q[4].w * sc[2]);                 \
    w_.z = pk2((float)q[5].x * sc[2], (float)q[5].y * sc[2]);                 \
    w_.w = pk2((float)q[5].z * sc[2], (float)q[5].w * sc[2]);                 \
    *(uint4*)&Bu_[sidx0] = w_;                                                \
    w_.x = pk2((float)q[6].x * sc[3], (float)q[6].y * sc[3]);                 \
    w_.y = pk2((float)q[6].z * sc[3], (float)q[6].w * sc[3]);                 \
    w_.z = pk2((float)q[7].x * sc[3], (float)q[7].y * sc[3]);                 \
    w_.w = pk2((float)q[7].z * sc[3], (float)q[7].w * sc[3]);                 \
    *(uint4*)&Bu_[sidx1] = w_;                                                \
  } while (0)

  f32x4 accg[4][4], accu[4][4];
  const f32x4 zero = {0.f, 0.f, 0.f, 0.f};
#pragma unroll
  for (int i = 0; i < 4; ++i)
#pragma unroll
    for (int j = 0; j < 4; ++j) { accg[i][j] = zero; accu[i][j] = zero; }

  // prologue: stage tile 0
  GU_ISSUEA(0, 0);
  GU_LOADB(0);
  GU_WRITEB(0);
  __syncthreads();

  const int NK = HDIM / 64;
#pragma unroll 1
  for (int kt = 0; kt < NK; ++kt) {
    const int RD = kt & 1, WR = RD ^ 1;
    const int kta = (kt + 1 < NK) ? kt + 1 : NK - 1;
    GU_ISSUEA(kta, WR);
    __builtin_amdgcn_sched_barrier(0);
    GU_LOADB(kta);
    __builtin_amdgcn_sched_barrier(0);
    // ---- compute tile kt ----
    {
      const unsigned short* Ab  = (const unsigned short*)As + RD * 16384;
      const unsigned short* Bgb = (const unsigned short*)Bg + RD * 8192;
      const unsigned short* Bub = (const unsigned short*)Bu + RD * 8192;
      __builtin_amdgcn_s_setprio(1);
#pragma unroll
      for (int ks = 0; ks < 2; ++ks) {
        const int soff = (((ks << 2) + lc) ^ (lr & 7)) << 3;
        bf16x8 af[4];
#pragma unroll
        for (int mi = 0; mi < 4; ++mi)
          af[mi] = *(const bf16x8*)&Ab[(wm * 64 + mi * 16 + lr) * 64 + soff];
#pragma unroll
        for (int ni = 0; ni < 4; ++ni) {
          bf16x8 bg = *(const bf16x8*)&Bgb[(wn * 64 + ni * 16 + lr) * 64 + soff];
          bf16x8 bu = *(const bf16x8*)&Bub[(wn * 64 + ni * 16 + lr) * 64 + soff];
#pragma unroll
          for (int mi = 0; mi < 4; ++mi) {
            accg[mi][ni] = __builtin_amdgcn_mfma_f32_16x16x32_bf16(af[mi], bg, accg[mi][ni], 0, 0, 0);
            accu[mi][ni] = __builtin_amdgcn_mfma_f32_16x16x32_bf16(af[mi], bu, accu[mi][ni], 0, 0, 0);
          }
        }
      }
      __builtin_amdgcn_s_setprio(0);
    }
    __builtin_amdgcn_sched_barrier(0);
    GU_WRITEB(WR);             // dequant this iter's loads -> other parity
    __syncthreads();           // one barrier per K-step
  }

  // ---- epilogue: silu(g)*u -> bf16 ----
  const int r0 = m0 + wm * 64, c0 = n0 + wn * 64;
#pragma unroll
  for (int mi = 0; mi < 4; ++mi)
#pragma unroll
    for (int ni = 0; ni < 4; ++ni)
#pragma unroll
      for (int r = 0; r < 4; ++r) {
        float g = accg[mi][ni][r], u = accu[mi][ni][r];
        float sv = g / (1.f + __expf(-g));
        int row = r0 + mi * 16 + lc * 4 + r;
        int col = c0 + ni * 16 + lr;
        inter[(long)row * IDIM + col] = f2bf(sv * u);
      }
#undef GU_ISSUEA
#undef GU_LOADB
#undef GU_WRITEB
}

// ================= down GEMM =================
// 256x128 tile, BK=64, counted-vmcnt cross-barrier pipeline (B depth-2).
__global__ __launch_bounds__(512, 2) void down_kernel(
    const unsigned short* __restrict__ inter,
    const int* __restrict__ dq, const float* __restrict__ dsc,
    float* __restrict__ out)
{
  __shared__ unsigned short As[2 * 256 * 64];  // 64 KB dbuf
  __shared__ unsigned short Bs[2 * 128 * 64];  // 32 KB dbuf

  const int tid  = threadIdx.x;
  const int lane = tid & 63;
  const int wid  = tid >> 6;
  const int wm   = wid >> 1, wn = wid & 1;
  const int p  = blockIdx.x;                 // 512 blocks
  const int l  = (p & 7) * 64 + (p >> 3);
  const int m0 = (l & 15) * 256;
  const int n0 = (l >> 4) * 128;
  const int lr = lane & 15, lc = lane >> 4;

  const int ra   = tid >> 3;
  const int scol = ((tid & 7) ^ (ra & 7)) << 3;
  const unsigned short* pa = inter + (long)(m0 + ra) * IDIM + scol;
  unsigned short* lbase = (unsigned short*)As + wid * 512;

  const int rb  = tid >> 3;
  const int cb  = (tid & 7) << 3;
  const int swz = ((tid & 7) ^ (rb & 7)) << 3;
  const int sidx0 = rb * 64 + swz;
  const int sidx1 = (64 + rb) * 64 + swz;
  const int*   pd0 = dq + (long)(n0 + rb) * IDIM + cb;
  const int*   pd1 = pd0 + 64 * IDIM;
  const float* ps0 = dsc + (n0 + rb) * (IDIM / GRP);
  const float* ps1 = ps0 + 64 * (IDIM / GRP);

  int4 q0[4], q1[4];     // two raw-weight reg sets (tile k -> set[k&1])
  float sc0[2], sc1[2];

#define DN_ISSUEA(KTA, WRP) do {                                              \
    const unsigned short* g_ = pa + (KTA) * 64;                               \
    unsigned short* l_ = lbase + (WRP) * 16384;                               \
    _Pragma("unroll")                                                         \
    for (int it = 0; it < 4; ++it)                                            \
      __builtin_amdgcn_global_load_lds(                                       \
          (const __attribute__((address_space(1))) unsigned int*)(g_ + it * 64 * IDIM), \
          (__attribute__((address_space(3))) unsigned int*)(l_ + it * 4096), 16, 0, 0); \
  } while (0)

#define DN_LOADB(Q, KT) do { const int kk_ = (KT) << 6;                       \
    Q[0] = *(const int4*)(pd0 + kk_); Q[1] = *(const int4*)(pd0 + kk_ + 4);   \
    Q[2] = *(const int4*)(pd1 + kk_); Q[3] = *(const int4*)(pd1 + kk_ + 4);   \
  } while (0)

#define DN_SCALES(S, KT) do { const int so_ = (KT) >> 1;                      \
    S[0] = ps0[so_]; S[1] = ps1[so_]; } while (0)

#define DN_WRITEB(Q, S, WRP) do {                                             \
    unsigned short* B_ = (unsigned short*)Bs + (WRP) * 8192;                  \
    uint4 w_;                                                                 \
    w_.x = pk2((float)Q[0].x * S[0], (float)Q[0].y * S[0]);                   \
    w_.y = pk2((float)Q[0].z * S[0], (float)Q[0].w * S[0]);                   \
    w_.z = pk2((float)Q[1].x * S[0], (float)Q[1].y * S[0]);                   \
    w_.w = pk2((float)Q[1].z * S[0], (float)Q[1].w * S[0]);                   \
    *(uint4*)&B_[sidx0] = w_;                                                 \
    w_.x = pk2((float)Q[2].x * S[1], (float)Q[2].y * S[1]);                   \
    w_.y = pk2((float)Q[2].z * S[1], (float)Q[2].w * S[1]);                   \
    w_.z = pk2((float)Q[3].x * S[1], (float)Q[3].y * S[1]);                   \
    w_.w = pk2((float)Q[3].z * S[1], (float)Q[3].w * S[1]);                   \
    *(uint4*)&B_[sidx1] = w_;                                                 \
  } while (0)

#define DN_COMPUTE(RDP) do {                                                  \
    const unsigned short* Ab_ = (const unsigned short*)As + (RDP) * 16384;    \
    const unsigned short* Bb_ = (const unsigned short*)Bs + (RDP) * 8192;     \
    __builtin_amdgcn_s_setprio(1);                                            \
    _Pragma("unroll")                                                         \
    for (int ks = 0; ks < 2; ++ks) {                                          \
      const int soff = (((ks << 2) + lc) ^ (lr & 7)) << 3;                    \
      bf16x8 af[4], bf[4];                                                    \
      _Pragma("unroll")                                                       \
      for (int mi = 0; mi < 4; ++mi)                                          \
        af[mi] = *(const bf16x8*)&Ab_[(wm * 64 + mi * 16 + lr) * 64 + soff];  \
      _Pragma("unroll")                                                       \
      for (int ni = 0; ni < 4; ++ni)                                          \
        bf[ni] = *(const bf16x8*)&Bb_[(wn * 64 + ni * 16 + lr) * 64 + soff];  \
      _Pragma("unroll")                                                       \
      for (int mi = 0; mi < 4; ++mi)                                          \
        _Pragma("unroll")                                                     \
        for (int ni = 0; ni < 4; ++ni)                                        \
          acc[mi][ni] = __builtin_amdgcn_mfma_f32_16x16x32_bf16(af[mi], bf[ni], acc[mi][ni], 0, 0, 0); \
    }                                                                         \
    __builtin_amdgcn_s_setprio(0);                                            \
  } while (0)

// one pipelined iteration: loads tile KT+2 into QL/SL, uses QU/SU for tile KT+1
#define DN_ITER(KT, QL, SL, QU, SU) do {                                      \
    const int RD_ = (KT) & 1, WR_ = RD_ ^ 1;                                  \
    const int kta_ = ((KT) + 1 < NKD) ? (KT) + 1 : NKD - 1;                   \
    const int ktc_ = ((KT) + 2 < NKD) ? (KT) + 2 : NKD - 1;                   \
    DN_ISSUEA(kta_, WR_);                                                     \
    __builtin_amdgcn_sched_barrier(0);                                        \
    DN_LOADB(QL, ktc_);                                                       \
    __builtin_amdgcn_sched_barrier(0);                                        \
    DN_COMPUTE(RD_);                                                          \
    __builtin_amdgcn_sched_barrier(0);                                        \
    DN_WRITEB(QU, SU, WR_);                                                   \
    __builtin_amdgcn_sched_barrier(0);                                        \
    asm volatile("s_waitcnt vmcnt(4)" ::: "memory"); /* retire own A gloads */ \
    __builtin_amdgcn_sched_barrier(0);                                        \
    DN_SCALES(SL, ktc_);                                                      \
    asm volatile("s_waitcnt lgkmcnt(0)" ::: "memory");                        \
    __builtin_amdgcn_s_barrier();                                             \
    __builtin_amdgcn_sched_barrier(0);                                        \
  } while (0)

  f32x4 acc[4][4];
  const f32x4 zero = {0.f, 0.f, 0.f, 0.f};
#pragma unroll
  for (int i = 0; i < 4; ++i)
#pragma unroll
    for (int j = 0; j < 4; ++j) acc[i][j] = zero;

  const int NKD = IDIM / 64;   // 224

  // prologue: A[0], B_lds[0] (tile0 via q0), regs q1 <- tile1
  DN_ISSUEA(0, 0);
  __builtin_amdgcn_sched_barrier(0);
  DN_LOADB(q0, 0); DN_SCALES(sc0, 0);
  DN_WRITEB(q0, sc0, 0);
  DN_LOADB(q1, 1); DN_SCALES(sc1, 1);
  asm volatile("s_waitcnt vmcnt(6)" ::: "memory");
  asm volatile("s_waitcnt lgkmcnt(0)" ::: "memory");
  __builtin_amdgcn_s_barrier();
  __builtin_amdgcn_sched_barrier(0);

#pragma unroll 1
  for (int kt = 0; kt < NKD; kt += 2) {
    DN_ITER(kt,     q0, sc0, q1, sc1);
    DN_ITER(kt + 1, q1, sc1, q0, sc0);
  }

  const int r0 = m0 + wm * 64, c0 = n0 + wn * 64;
#pragma unroll
  for (int mi = 0; mi < 4; ++mi)
#pragma unroll
    for (int ni = 0; ni < 4; ++ni)
#pragma unroll
      for (int r = 0; r < 4; ++r) {
        int row = r0 + mi * 16 + lc * 4 + r;
        int col = c0 + ni * 16 + lr;
        out[(long)row * HDIM + col] = acc[mi][ni][r];
      }
#undef DN_ISSUEA
#undef DN_LOADB
#undef DN_SCALES
#undef DN_WRITEB
#undef DN_COMPUTE
#undef DN_ITER
}

extern "C" void kernel_launch(void* const* d_in, const int* in_sizes, int n_in,
                              void* d_out, int out_size, void* d_ws, size_t ws_size,
                              hipStream_t stream) {
  const float* x   = (const float*)d_in[0];
  const int*   gq  = (const int*)d_in[1];
  const float* gsc = (const float*)d_in[2];
  const int*   uq  = (const int*)d_in[3];
  const float* usc = (const float*)d_in[4];
  const int*   dq  = (const int*)d_in[5];
  const float* dsc = (const float*)d_in[6];
  float* out = (float*)d_out;

  // ws layout: xb [MTOK*HDIM] bf16 (32 MiB) | inter [MTOK*IDIM] bf16 (112 MiB)
  unsigned short* xb    = (unsigned short*)d_ws;
  unsigned short* inter = xb + (size_t)MTOK * HDIM;

  hipLaunchKernelGGL(cvt_x_kernel, dim3(2048), dim3(256), 0, stream, x, xb);
  hipLaunchKernelGGL(gateup_kernel, dim3(1792), dim3(512), 0, stream,
                     xb, gq, gsc, uq, usc, inter);
  hipLaunchKernelGGL(down_kernel, dim3(512), dim3(512), 0, stream,
                     inter, dq, dsc, out);
}